// Round 4
// baseline (300.670 us; speedup 1.0000x reference)
//
#include <hip/hip_runtime.h>

typedef __attribute__((ext_vector_type(8))) short bf16x8;
typedef __attribute__((ext_vector_type(8))) unsigned short u16x8;
typedef __attribute__((ext_vector_type(4))) float f32x4;

constexpr int BH  = 64;    // B*H
constexpr int SEQ = 4096;  // N
constexpr int DIM = 64;    // D
constexpr int PM  = 256;   // M (proj_len)
constexpr size_t PLANE = (size_t)BH * PM * DIM;   // 1,048,576 elements

__device__ __forceinline__ unsigned short f2bf(float f){
    unsigned int u = __float_as_uint(f);
    return (unsigned short)((u + 0x7fffu + ((u >> 16) & 1u)) >> 16);
}
__device__ __forceinline__ float bf2f(unsigned short h){
    return __uint_as_float(((unsigned int)h) << 16);
}

// ---------------- kernel 1: E [N][M] f32 -> Et_hi/Et_lo [M][N] bf16 (split) ----------------
__global__ __launch_bounds__(256) void prep_e_kernel(const float* __restrict__ E,
                                                     unsigned short* __restrict__ Et_hi,
                                                     unsigned short* __restrict__ Et_lo){
    __shared__ float T[64][65];
    int n0 = (blockIdx.x & 63) * 64;
    int m0 = (blockIdx.x >> 6) * 64;
    int t = threadIdx.x;
    #pragma unroll
    for (int i = 0; i < 16; ++i){
        int idx = t + i * 256;
        int nl = idx >> 6, ml = idx & 63;
        T[nl][ml] = E[(size_t)(n0 + nl) * PM + (m0 + ml)];
    }
    __syncthreads();
    #pragma unroll
    for (int i = 0; i < 16; ++i){
        int idx = t + i * 256;
        int ml = idx >> 6, nl = idx & 63;
        float v = T[nl][ml];
        unsigned short h = f2bf(v);
        unsigned short lo = f2bf(v - bf2f(h));
        size_t o = (size_t)(m0 + ml) * SEQ + (n0 + nl);
        Et_hi[o] = h;
        Et_lo[o] = lo;
    }
}

// ---------------- kernel 2: projection partials, K/V read exactly once ----------------
__global__ __launch_bounds__(256, 2) void proj_partial_kernel(const float* __restrict__ K,
                                                              const float* __restrict__ V,
                                                              const unsigned short* __restrict__ Et_hi,
                                                              const unsigned short* __restrict__ Et_lo,
                                                              float* __restrict__ PK,
                                                              float* __restrict__ PV){
    __shared__ unsigned short Kh[64][72], Kl[64][72], Vh[64][72];
    int bid   = blockIdx.x;
    int s     = bid & 7;          // default round-robin: same-s -> same XCD (shares Et slice)
    int bh    = bid >> 3;
    int nbase = s * (SEQ / 8);
    int t = threadIdx.x;
    int w = t >> 6, l = t & 63, l15 = l & 15, lg = l >> 4;
    int m0w = w * 64;

    const float* Kb = K + (size_t)bh * SEQ * DIM;
    const float* Vb = V + (size_t)bh * SEQ * DIM;

    f32x4 accK[4][4], accV[4][4];
    #pragma unroll
    for (int i = 0; i < 4; ++i)
        #pragma unroll
        for (int j = 0; j < 4; ++j){ accK[i][j] = (f32x4)0.0f; accV[i][j] = (f32x4)0.0f; }

    for (int n0 = nbase; n0 < nbase + SEQ / 8; n0 += 64){
        bf16x8 eh[2][4], el[2][4];
        #pragma unroll
        for (int nk = 0; nk < 2; ++nk){
            #pragma unroll
            for (int ms = 0; ms < 4; ++ms){
                size_t off = (size_t)(m0w + ms * 16 + l15) * SEQ + (n0 + nk * 32 + lg * 8);
                eh[nk][ms] = *reinterpret_cast<const bf16x8*>(Et_hi + off);
                el[nk][ms] = *reinterpret_cast<const bf16x8*>(Et_lo + off);
            }
        }
        {
            int d  = t & 63;
            int ng = t >> 6;
            #pragma unroll
            for (int p = 0; p < 2; ++p){
                int nb = p * 32 + ng * 8;
                u16x8 kh, kl, vh;
                #pragma unroll
                for (int i = 0; i < 8; ++i){
                    float kv = Kb[(size_t)(n0 + nb + i) * DIM + d];
                    unsigned short h = f2bf(kv);
                    kh[i] = (short)h;
                    kl[i] = (short)f2bf(kv - bf2f(h));
                    float vv = Vb[(size_t)(n0 + nb + i) * DIM + d];
                    vh[i] = (short)f2bf(vv);
                }
                *reinterpret_cast<u16x8*>(&Kh[d][nb]) = kh;
                *reinterpret_cast<u16x8*>(&Kl[d][nb]) = kl;
                *reinterpret_cast<u16x8*>(&Vh[d][nb]) = vh;
            }
        }
        __syncthreads();
        #pragma unroll
        for (int nk = 0; nk < 2; ++nk){
            int kb = nk * 32 + lg * 8;
            #pragma unroll
            for (int dt = 0; dt < 4; ++dt){
                bf16x8 kh = *reinterpret_cast<const bf16x8*>(&Kh[dt * 16 + l15][kb]);
                bf16x8 kl = *reinterpret_cast<const bf16x8*>(&Kl[dt * 16 + l15][kb]);
                bf16x8 vh = *reinterpret_cast<const bf16x8*>(&Vh[dt * 16 + l15][kb]);
                #pragma unroll
                for (int ms = 0; ms < 4; ++ms){
                    accK[ms][dt] = __builtin_amdgcn_mfma_f32_16x16x32_bf16(eh[nk][ms], kh, accK[ms][dt], 0, 0, 0);
                    accK[ms][dt] = __builtin_amdgcn_mfma_f32_16x16x32_bf16(eh[nk][ms], kl, accK[ms][dt], 0, 0, 0);
                    accK[ms][dt] = __builtin_amdgcn_mfma_f32_16x16x32_bf16(el[nk][ms], kh, accK[ms][dt], 0, 0, 0);
                    accV[dt][ms] = __builtin_amdgcn_mfma_f32_16x16x32_bf16(vh, eh[nk][ms], accV[dt][ms], 0, 0, 0);
                }
            }
        }
        __syncthreads();
    }

    float* PKb = PK + ((size_t)s * BH + bh) * PM * DIM;
    float* PVb = PV + ((size_t)s * BH + bh) * DIM * PM;
    #pragma unroll
    for (int ms = 0; ms < 4; ++ms){
        #pragma unroll
        for (int dt = 0; dt < 4; ++dt){
            #pragma unroll
            for (int j = 0; j < 4; ++j){
                int mg = m0w + ms * 16 + lg * 4 + j;
                int dg = dt * 16 + l15;
                PKb[(size_t)mg * DIM + dg] = accK[ms][dt][j];
                int dr = dt * 16 + lg * 4 + j;
                int mc = m0w + ms * 16 + l15;
                PVb[(size_t)dr * PM + mc] = accV[dt][ms][j];
            }
        }
    }
}

// ---------------- kernel 2b: reduce 8 partials -> Kp_hi/Kp_lo/Vpt ----------------
__global__ __launch_bounds__(256) void reduce_kernel(const float* __restrict__ PK,
                                                     const float* __restrict__ PV,
                                                     unsigned short* __restrict__ Kp_hi,
                                                     unsigned short* __restrict__ Kp_lo,
                                                     unsigned short* __restrict__ Vpt){
    size_t e4 = (size_t)blockIdx.x * 256 + threadIdx.x;
    const float4* PK4 = reinterpret_cast<const float4*>(PK);
    const float4* PV4 = reinterpret_cast<const float4*>(PV);
    size_t stride4 = PLANE / 4;

    float4 k = PK4[e4];
    float4 v = PV4[e4];
    #pragma unroll
    for (int s = 1; s < 8; ++s){
        float4 a = PK4[e4 + (size_t)s * stride4];
        float4 b = PV4[e4 + (size_t)s * stride4];
        k.x += a.x; k.y += a.y; k.z += a.z; k.w += a.w;
        v.x += b.x; v.y += b.y; v.z += b.z; v.w += b.w;
    }
    float kk[4] = {k.x, k.y, k.z, k.w};
    float vv[4] = {v.x, v.y, v.z, v.w};
    typedef __attribute__((ext_vector_type(4))) unsigned short u16x4;
    u16x4 hi, lo, vb;
    #pragma unroll
    for (int i = 0; i < 4; ++i){
        unsigned short h = f2bf(kk[i]);
        hi[i] = h;
        lo[i] = f2bf(kk[i] - bf2f(h));
        vb[i] = f2bf(vv[i]);
    }
    *reinterpret_cast<u16x4*>(Kp_hi + e4 * 4) = hi;
    *reinterpret_cast<u16x4*>(Kp_lo + e4 * 4) = lo;
    *reinterpret_cast<u16x4*>(Vpt   + e4 * 4) = vb;
}

// ---------------- kernel 3: attention — zero-barrier, B-frags direct from L2 ----------------
// P redistribution is wave-private (wave w touches rows [w*16, w*16+16) only),
// so the kernel has NO __syncthreads at all: 4 blocks/CU x 4 waves run freely.
__global__ __launch_bounds__(256, 4) void attn_kernel(const float* __restrict__ Q,
                                                      const unsigned short* __restrict__ Kp_hi,
                                                      const unsigned short* __restrict__ Kp_lo,
                                                      const unsigned short* __restrict__ Vpt,
                                                      float* __restrict__ Out){
    __shared__ unsigned short P[64][262];   // stride 131 dwords (odd) -> <=2-way conflicts

    int bid  = blockIdx.x;
    int orig = (bid & 7) * 512 + (bid >> 3);  // XCD-chunked: 8 heads per XCD
    int bh   = orig >> 6;
    int q0   = (orig & 63) * 64;
    int t = threadIdx.x;
    int w = t >> 6, l = t & 63, l15 = l & 15, lg = l >> 4;

    // Q fragments (x 1/8 scale) straight from global into registers, split hi/lo
    bf16x8 qh[2], ql[2];
    {
        const float* Qb = Q + ((size_t)bh * SEQ + q0 + w * 16 + l15) * DIM;
        #pragma unroll
        for (int nk = 0; nk < 2; ++nk){
            float4 a = *reinterpret_cast<const float4*>(Qb + nk * 32 + lg * 8);
            float4 b = *reinterpret_cast<const float4*>(Qb + nk * 32 + lg * 8 + 4);
            float vals[8] = {a.x, a.y, a.z, a.w, b.x, b.y, b.z, b.w};
            #pragma unroll
            for (int i = 0; i < 8; ++i){
                float v = vals[i] * 0.125f;
                unsigned short h = f2bf(v);
                qh[nk][i] = (short)h;
                ql[nk][i] = (short)f2bf(v - bf2f(h));
            }
        }
    }

    // QK^T: B-fragments direct from global (L2-resident per XCD)
    f32x4 sa[16];
    #pragma unroll
    for (int i = 0; i < 16; ++i) sa[i] = (f32x4)0.0f;
    const unsigned short* KHb = Kp_hi + (size_t)bh * PM * DIM;
    const unsigned short* KLb = Kp_lo + (size_t)bh * PM * DIM;
    #pragma unroll
    for (int mi = 0; mi < 16; ++mi){
        #pragma unroll
        for (int nk = 0; nk < 2; ++nk){
            size_t off = (size_t)(mi * 16 + l15) * DIM + nk * 32 + lg * 8;
            bf16x8 bh_ = *reinterpret_cast<const bf16x8*>(KHb + off);
            bf16x8 bl_ = *reinterpret_cast<const bf16x8*>(KLb + off);
            sa[mi] = __builtin_amdgcn_mfma_f32_16x16x32_bf16(qh[nk], bh_, sa[mi], 0, 0, 0);
            sa[mi] = __builtin_amdgcn_mfma_f32_16x16x32_bf16(qh[nk], bl_, sa[mi], 0, 0, 0);
            sa[mi] = __builtin_amdgcn_mfma_f32_16x16x32_bf16(ql[nk], bh_, sa[mi], 0, 0, 0);
        }
    }

    // softmax over m=256 (cols spread over 16 lanes x 16 regs; rows = lg*4+j)
    float inv[4];
    #pragma unroll
    for (int j = 0; j < 4; ++j){
        float mx = sa[0][j];
        #pragma unroll
        for (int mi = 1; mi < 16; ++mi) mx = fmaxf(mx, sa[mi][j]);
        #pragma unroll
        for (int o = 1; o < 16; o <<= 1) mx = fmaxf(mx, __shfl_xor(mx, o, 64));
        float sum = 0.0f;
        #pragma unroll
        for (int mi = 0; mi < 16; ++mi){
            float p = __expf(sa[mi][j] - mx);
            sa[mi][j] = p;
            sum += p;
        }
        #pragma unroll
        for (int o = 1; o < 16; o <<= 1) sum += __shfl_xor(sum, o, 64);
        inv[j] = 1.0f / sum;
    }

    // wave-private P redistribution through LDS (no barrier needed)
    #pragma unroll
    for (int mi = 0; mi < 16; ++mi){
        #pragma unroll
        for (int j = 0; j < 4; ++j){
            P[w * 16 + lg * 4 + j][mi * 16 + l15] = f2bf(sa[mi][j]);
        }
    }

    // PV: out[q][d] = sum_m P[q][m] * Vpt[d][m]  (B-frags direct from global)
    f32x4 oacc[4];
    #pragma unroll
    for (int i = 0; i < 4; ++i) oacc[i] = (f32x4)0.0f;
    const unsigned short* Vb = Vpt + (size_t)bh * DIM * PM;
    #pragma unroll
    for (int mk = 0; mk < 8; ++mk){
        bf16x8 ap = *reinterpret_cast<const bf16x8*>(&P[w * 16 + l15][mk * 32 + lg * 8]);
        #pragma unroll
        for (int dt = 0; dt < 4; ++dt){
            bf16x8 bv = *reinterpret_cast<const bf16x8*>(Vb + (size_t)(dt * 16 + l15) * PM + mk * 32 + lg * 8);
            oacc[dt] = __builtin_amdgcn_mfma_f32_16x16x32_bf16(ap, bv, oacc[dt], 0, 0, 0);
        }
    }

    #pragma unroll
    for (int dt = 0; dt < 4; ++dt){
        #pragma unroll
        for (int j = 0; j < 4; ++j){
            int qg = q0 + w * 16 + lg * 4 + j;
            Out[((size_t)bh * SEQ + qg) * DIM + dt * 16 + l15] = oacc[dt][j] * inv[j];
        }
    }
}

extern "C" void kernel_launch(void* const* d_in, const int* in_sizes, int n_in,
                              void* d_out, int out_size, void* d_ws, size_t ws_size,
                              hipStream_t stream){
    const float* Q = (const float*)d_in[0];
    const float* K = (const float*)d_in[1];
    const float* V = (const float*)d_in[2];
    const float* E = (const float*)d_in[3];
    float* out = (float*)d_out;

    unsigned short* Et_hi = (unsigned short*)d_ws;                       // [M][N]
    unsigned short* Et_lo = Et_hi + (size_t)PM * SEQ;                    // [M][N]
    unsigned short* Kp_hi = Et_lo + (size_t)PM * SEQ;                    // [BH][M][D]
    unsigned short* Kp_lo = Kp_hi + PLANE;                               // [BH][M][D]
    unsigned short* Vpt   = Kp_lo + PLANE;                               // [BH][D][M]
    size_t base_bytes = ((size_t)PM * SEQ * 2 + PLANE * 3) * sizeof(unsigned short);
    float* PK = reinterpret_cast<float*>((char*)d_ws + base_bytes);      // [8][BH][M][D]
    float* PV = PK + 8 * PLANE;                                          // [8][BH][D][M]

    prep_e_kernel<<<256, 256, 0, stream>>>(E, Et_hi, Et_lo);
    proj_partial_kernel<<<512, 256, 0, stream>>>(K, V, Et_hi, Et_lo, PK, PV);
    reduce_kernel<<<PLANE / 4 / 256, 256, 0, stream>>>(PK, PV, Kp_hi, Kp_lo, Vpt);
    attn_kernel<<<4096, 256, 0, stream>>>(Q, Kp_hi, Kp_lo, Vpt, out);
}

// Round 5
// 211.036 us; speedup vs baseline: 1.4247x; 1.4247x over previous
//
#include <hip/hip_runtime.h>

typedef __attribute__((ext_vector_type(8))) short bf16x8;
typedef __attribute__((ext_vector_type(8))) unsigned short u16x8;
typedef __attribute__((ext_vector_type(4))) float f32x4;

constexpr int BH  = 64;    // B*H
constexpr int SEQ = 4096;  // N
constexpr int DIM = 64;    // D
constexpr int PM  = 256;   // M (proj_len)
constexpr size_t PLANE = (size_t)BH * PM * DIM;   // 1,048,576 elements

__device__ __forceinline__ unsigned short f2bf(float f){
    unsigned int u = __float_as_uint(f);
    return (unsigned short)((u + 0x7fffu + ((u >> 16) & 1u)) >> 16);
}
__device__ __forceinline__ float bf2f(unsigned short h){
    return __uint_as_float(((unsigned int)h) << 16);
}

// ---------------- kernel 1: E [N][M] f32 -> Et_hi/Et_lo [M][N] bf16 (split) ----------------
__global__ __launch_bounds__(256) void prep_e_kernel(const float* __restrict__ E,
                                                     unsigned short* __restrict__ Et_hi,
                                                     unsigned short* __restrict__ Et_lo){
    __shared__ float T[64][65];
    int n0 = (blockIdx.x & 63) * 64;
    int m0 = (blockIdx.x >> 6) * 64;
    int t = threadIdx.x;
    #pragma unroll
    for (int i = 0; i < 16; ++i){
        int idx = t + i * 256;
        int nl = idx >> 6, ml = idx & 63;
        T[nl][ml] = E[(size_t)(n0 + nl) * PM + (m0 + ml)];
    }
    __syncthreads();
    #pragma unroll
    for (int i = 0; i < 16; ++i){
        int idx = t + i * 256;
        int ml = idx >> 6, nl = idx & 63;
        float v = T[nl][ml];
        unsigned short h = f2bf(v);
        unsigned short lo = f2bf(v - bf2f(h));
        size_t o = (size_t)(m0 + ml) * SEQ + (n0 + nl);
        Et_hi[o] = h;
        Et_lo[o] = lo;
    }
}

// ---------------- kernel 2: projection partials, K/V read exactly once ----------------
__global__ __launch_bounds__(256, 2) void proj_partial_kernel(const float* __restrict__ K,
                                                              const float* __restrict__ V,
                                                              const unsigned short* __restrict__ Et_hi,
                                                              const unsigned short* __restrict__ Et_lo,
                                                              float* __restrict__ PK,
                                                              float* __restrict__ PV){
    __shared__ unsigned short Kh[64][72], Kl[64][72], Vh[64][72];
    int bid   = blockIdx.x;
    int s     = bid & 7;          // default round-robin: same-s -> same XCD (shares Et slice)
    int bh    = bid >> 3;
    int nbase = s * (SEQ / 8);
    int t = threadIdx.x;
    int w = t >> 6, l = t & 63, l15 = l & 15, lg = l >> 4;
    int m0w = w * 64;

    const float* Kb = K + (size_t)bh * SEQ * DIM;
    const float* Vb = V + (size_t)bh * SEQ * DIM;

    f32x4 accK[4][4], accV[4][4];
    #pragma unroll
    for (int i = 0; i < 4; ++i)
        #pragma unroll
        for (int j = 0; j < 4; ++j){ accK[i][j] = (f32x4)0.0f; accV[i][j] = (f32x4)0.0f; }

    for (int n0 = nbase; n0 < nbase + SEQ / 8; n0 += 64){
        bf16x8 eh[2][4], el[2][4];
        #pragma unroll
        for (int nk = 0; nk < 2; ++nk){
            #pragma unroll
            for (int ms = 0; ms < 4; ++ms){
                size_t off = (size_t)(m0w + ms * 16 + l15) * SEQ + (n0 + nk * 32 + lg * 8);
                eh[nk][ms] = *reinterpret_cast<const bf16x8*>(Et_hi + off);
                el[nk][ms] = *reinterpret_cast<const bf16x8*>(Et_lo + off);
            }
        }
        {
            int d  = t & 63;
            int ng = t >> 6;
            #pragma unroll
            for (int p = 0; p < 2; ++p){
                int nb = p * 32 + ng * 8;
                u16x8 kh, kl, vh;
                #pragma unroll
                for (int i = 0; i < 8; ++i){
                    float kv = Kb[(size_t)(n0 + nb + i) * DIM + d];
                    unsigned short h = f2bf(kv);
                    kh[i] = (short)h;
                    kl[i] = (short)f2bf(kv - bf2f(h));
                    float vv = Vb[(size_t)(n0 + nb + i) * DIM + d];
                    vh[i] = (short)f2bf(vv);
                }
                *reinterpret_cast<u16x8*>(&Kh[d][nb]) = kh;
                *reinterpret_cast<u16x8*>(&Kl[d][nb]) = kl;
                *reinterpret_cast<u16x8*>(&Vh[d][nb]) = vh;
            }
        }
        __syncthreads();
        #pragma unroll
        for (int nk = 0; nk < 2; ++nk){
            int kb = nk * 32 + lg * 8;
            #pragma unroll
            for (int dt = 0; dt < 4; ++dt){
                bf16x8 kh = *reinterpret_cast<const bf16x8*>(&Kh[dt * 16 + l15][kb]);
                bf16x8 kl = *reinterpret_cast<const bf16x8*>(&Kl[dt * 16 + l15][kb]);
                bf16x8 vh = *reinterpret_cast<const bf16x8*>(&Vh[dt * 16 + l15][kb]);
                #pragma unroll
                for (int ms = 0; ms < 4; ++ms){
                    accK[ms][dt] = __builtin_amdgcn_mfma_f32_16x16x32_bf16(eh[nk][ms], kh, accK[ms][dt], 0, 0, 0);
                    accK[ms][dt] = __builtin_amdgcn_mfma_f32_16x16x32_bf16(eh[nk][ms], kl, accK[ms][dt], 0, 0, 0);
                    accK[ms][dt] = __builtin_amdgcn_mfma_f32_16x16x32_bf16(el[nk][ms], kh, accK[ms][dt], 0, 0, 0);
                    accV[dt][ms] = __builtin_amdgcn_mfma_f32_16x16x32_bf16(vh, eh[nk][ms], accV[dt][ms], 0, 0, 0);
                }
            }
        }
        __syncthreads();
    }

    float* PKb = PK + ((size_t)s * BH + bh) * PM * DIM;
    float* PVb = PV + ((size_t)s * BH + bh) * DIM * PM;
    #pragma unroll
    for (int ms = 0; ms < 4; ++ms){
        #pragma unroll
        for (int dt = 0; dt < 4; ++dt){
            #pragma unroll
            for (int j = 0; j < 4; ++j){
                int mg = m0w + ms * 16 + lg * 4 + j;
                int dg = dt * 16 + l15;
                PKb[(size_t)mg * DIM + dg] = accK[ms][dt][j];
                int dr = dt * 16 + lg * 4 + j;
                int mc = m0w + ms * 16 + l15;
                PVb[(size_t)dr * PM + mc] = accV[dt][ms][j];
            }
        }
    }
}

// ---------------- kernel 2b: reduce 8 partials -> Kp_hi/Kp_lo/Vpt ----------------
__global__ __launch_bounds__(256) void reduce_kernel(const float* __restrict__ PK,
                                                     const float* __restrict__ PV,
                                                     unsigned short* __restrict__ Kp_hi,
                                                     unsigned short* __restrict__ Kp_lo,
                                                     unsigned short* __restrict__ Vpt){
    size_t e4 = (size_t)blockIdx.x * 256 + threadIdx.x;
    const float4* PK4 = reinterpret_cast<const float4*>(PK);
    const float4* PV4 = reinterpret_cast<const float4*>(PV);
    size_t stride4 = PLANE / 4;

    float4 k = PK4[e4];
    float4 v = PV4[e4];
    #pragma unroll
    for (int s = 1; s < 8; ++s){
        float4 a = PK4[e4 + (size_t)s * stride4];
        float4 b = PV4[e4 + (size_t)s * stride4];
        k.x += a.x; k.y += a.y; k.z += a.z; k.w += a.w;
        v.x += b.x; v.y += b.y; v.z += b.z; v.w += b.w;
    }
    float kk[4] = {k.x, k.y, k.z, k.w};
    float vv[4] = {v.x, v.y, v.z, v.w};
    typedef __attribute__((ext_vector_type(4))) unsigned short u16x4;
    u16x4 hi, lo, vb;
    #pragma unroll
    for (int i = 0; i < 4; ++i){
        unsigned short h = f2bf(kk[i]);
        hi[i] = h;
        lo[i] = f2bf(kk[i] - bf2f(h));
        vb[i] = f2bf(vv[i]);
    }
    *reinterpret_cast<u16x4*>(Kp_hi + e4 * 4) = hi;
    *reinterpret_cast<u16x4*>(Kp_lo + e4 * 4) = lo;
    *reinterpret_cast<u16x4*>(Vpt   + e4 * 4) = vb;
}

// ---------------- kernel 3: attention ----------------
// grid 1024 = (bh x 16 q-chunks of 256). Stage the WHOLE head (Kp hi/lo + Vpt,
// 96 KB) in dynamic LDS once, ONE barrier, then 4 waves each process 64 q-rows
// (4 row-tiles of 16) with zero further barriers; P is wave-private LDS.
constexpr int ATTN_LDS_BYTES = (2 * 256 * 72 + 64 * 264 + 4 * 16 * 264) * 2;  // 141,312

__global__ __launch_bounds__(256, 1) void attn_kernel(const float* __restrict__ Q,
                                                      const unsigned short* __restrict__ Kp_hi,
                                                      const unsigned short* __restrict__ Kp_lo,
                                                      const unsigned short* __restrict__ Vpt,
                                                      float* __restrict__ Out){
    extern __shared__ unsigned short smem[];
    unsigned short (*Kh)[72]  = reinterpret_cast<unsigned short (*)[72]>(smem);              // [256][72]
    unsigned short (*Kl)[72]  = reinterpret_cast<unsigned short (*)[72]>(smem + 256 * 72);   // [256][72]
    unsigned short (*Vt)[264] = reinterpret_cast<unsigned short (*)[264]>(smem + 2 * 256 * 72); // [64][264]
    unsigned short* Pbase     = smem + 2 * 256 * 72 + 64 * 264;                              // 4 x [16][264]

    int bid  = blockIdx.x;
    int orig = (bid & 7) * 128 + (bid >> 3);  // XCD-chunked: 8 heads per XCD
    int bh   = orig >> 4;
    int q0   = (orig & 15) * 256;
    int t = threadIdx.x;
    int w = t >> 6, l = t & 63, l15 = l & 15, lg = l >> 4;
    unsigned short (*Pw)[264] = reinterpret_cast<unsigned short (*)[264]>(Pbase + w * 16 * 264);

    // ---- stage head slabs, flat & fully coalesced (16B per lane) ----
    const unsigned short* KHb = Kp_hi + (size_t)bh * PM * DIM;   // 16384 shorts
    const unsigned short* KLb = Kp_lo + (size_t)bh * PM * DIM;
    const unsigned short* VTb = Vpt   + (size_t)bh * DIM * PM;
    #pragma unroll
    for (int i = 0; i < 8; ++i){
        int idx = i * 256 + t;            // u16x8 index, 2048 vecs
        int r = idx >> 3;                 // 8 vecs per 64-short row
        int c = (idx & 7) * 8;
        u16x8 a = *reinterpret_cast<const u16x8*>(KHb + (size_t)idx * 8);
        u16x8 b = *reinterpret_cast<const u16x8*>(KLb + (size_t)idx * 8);
        *reinterpret_cast<u16x8*>(&Kh[r][c]) = a;
        *reinterpret_cast<u16x8*>(&Kl[r][c]) = b;
    }
    #pragma unroll
    for (int i = 0; i < 8; ++i){
        int idx = i * 256 + t;            // 2048 vecs
        int r = idx >> 5;                 // 32 vecs per 256-short row
        int c = (idx & 31) * 8;
        u16x8 a = *reinterpret_cast<const u16x8*>(VTb + (size_t)idx * 8);
        *reinterpret_cast<u16x8*>(&Vt[r][c]) = a;
    }
    __syncthreads();   // the ONLY barrier

    const float* Qw = Q   + ((size_t)bh * SEQ + q0 + w * 64) * DIM;
    float*       Ow = Out + ((size_t)bh * SEQ + q0 + w * 64) * DIM;

    for (int rt = 0; rt < 4; ++rt){
        // Q fragments (x 1/8 scale) straight from global, split hi/lo
        bf16x8 qh[2], ql[2];
        {
            const float* Qb = Qw + (size_t)(rt * 16 + l15) * DIM;
            #pragma unroll
            for (int nk = 0; nk < 2; ++nk){
                float4 a = *reinterpret_cast<const float4*>(Qb + nk * 32 + lg * 8);
                float4 b = *reinterpret_cast<const float4*>(Qb + nk * 32 + lg * 8 + 4);
                float vals[8] = {a.x, a.y, a.z, a.w, b.x, b.y, b.z, b.w};
                #pragma unroll
                for (int i = 0; i < 8; ++i){
                    float v = vals[i] * 0.125f;
                    unsigned short h = f2bf(v);
                    qh[nk][i] = (short)h;
                    ql[nk][i] = (short)f2bf(v - bf2f(h));
                }
            }
        }

        // QK^T from LDS
        f32x4 sa[16];
        #pragma unroll
        for (int i = 0; i < 16; ++i) sa[i] = (f32x4)0.0f;
        #pragma unroll
        for (int mi = 0; mi < 16; ++mi){
            #pragma unroll
            for (int nk = 0; nk < 2; ++nk){
                bf16x8 bh_ = *reinterpret_cast<const bf16x8*>(&Kh[mi * 16 + l15][nk * 32 + lg * 8]);
                bf16x8 bl_ = *reinterpret_cast<const bf16x8*>(&Kl[mi * 16 + l15][nk * 32 + lg * 8]);
                sa[mi] = __builtin_amdgcn_mfma_f32_16x16x32_bf16(qh[nk], bh_, sa[mi], 0, 0, 0);
                sa[mi] = __builtin_amdgcn_mfma_f32_16x16x32_bf16(qh[nk], bl_, sa[mi], 0, 0, 0);
                sa[mi] = __builtin_amdgcn_mfma_f32_16x16x32_bf16(ql[nk], bh_, sa[mi], 0, 0, 0);
            }
        }

        // softmax over m=256 (cols spread over 16 lanes x 16 regs; row = lg*4+j)
        float inv[4];
        #pragma unroll
        for (int j = 0; j < 4; ++j){
            float mx = sa[0][j];
            #pragma unroll
            for (int mi = 1; mi < 16; ++mi) mx = fmaxf(mx, sa[mi][j]);
            #pragma unroll
            for (int o = 1; o < 16; o <<= 1) mx = fmaxf(mx, __shfl_xor(mx, o, 64));
            float sum = 0.0f;
            #pragma unroll
            for (int mi = 0; mi < 16; ++mi){
                float p = __expf(sa[mi][j] - mx);
                sa[mi][j] = p;
                sum += p;
            }
            #pragma unroll
            for (int o = 1; o < 16; o <<= 1) sum += __shfl_xor(sum, o, 64);
            inv[j] = 1.0f / sum;
        }

        // wave-private P redistribution (no barrier; same-wave LDS RAW is ordered)
        #pragma unroll
        for (int mi = 0; mi < 16; ++mi){
            #pragma unroll
            for (int j = 0; j < 4; ++j){
                Pw[lg * 4 + j][mi * 16 + l15] = f2bf(sa[mi][j]);
            }
        }

        // PV from LDS
        f32x4 oacc[4];
        #pragma unroll
        for (int i = 0; i < 4; ++i) oacc[i] = (f32x4)0.0f;
        #pragma unroll
        for (int mk = 0; mk < 8; ++mk){
            bf16x8 ap = *reinterpret_cast<const bf16x8*>(&Pw[l15][mk * 32 + lg * 8]);
            #pragma unroll
            for (int dt = 0; dt < 4; ++dt){
                bf16x8 bv = *reinterpret_cast<const bf16x8*>(&Vt[dt * 16 + l15][mk * 32 + lg * 8]);
                oacc[dt] = __builtin_amdgcn_mfma_f32_16x16x32_bf16(ap, bv, oacc[dt], 0, 0, 0);
            }
        }

        #pragma unroll
        for (int dt = 0; dt < 4; ++dt){
            #pragma unroll
            for (int j = 0; j < 4; ++j){
                Ow[(size_t)(rt * 16 + lg * 4 + j) * DIM + dt * 16 + l15] = oacc[dt][j] * inv[j];
            }
        }
    }
}

extern "C" void kernel_launch(void* const* d_in, const int* in_sizes, int n_in,
                              void* d_out, int out_size, void* d_ws, size_t ws_size,
                              hipStream_t stream){
    const float* Q = (const float*)d_in[0];
    const float* K = (const float*)d_in[1];
    const float* V = (const float*)d_in[2];
    const float* E = (const float*)d_in[3];
    float* out = (float*)d_out;

    unsigned short* Et_hi = (unsigned short*)d_ws;                       // [M][N]
    unsigned short* Et_lo = Et_hi + (size_t)PM * SEQ;                    // [M][N]
    unsigned short* Kp_hi = Et_lo + (size_t)PM * SEQ;                    // [BH][M][D]
    unsigned short* Kp_lo = Kp_hi + PLANE;                               // [BH][M][D]
    unsigned short* Vpt   = Kp_lo + PLANE;                               // [BH][D][M]
    size_t base_bytes = ((size_t)PM * SEQ * 2 + PLANE * 3) * sizeof(unsigned short);
    float* PK = reinterpret_cast<float*>((char*)d_ws + base_bytes);      // [8][BH][M][D]
    float* PV = PK + 8 * PLANE;                                          // [8][BH][D][M]

    // opt-in to >64KB dynamic LDS (host-side attribute set; not a stream op,
    // so graph-capture safe; idempotent per call)
    hipFuncSetAttribute(reinterpret_cast<const void*>(attn_kernel),
                        hipFuncAttributeMaxDynamicSharedMemorySize, ATTN_LDS_BYTES);

    prep_e_kernel<<<256, 256, 0, stream>>>(E, Et_hi, Et_lo);
    proj_partial_kernel<<<512, 256, 0, stream>>>(K, V, Et_hi, Et_lo, PK, PV);
    reduce_kernel<<<PLANE / 4 / 256, 256, 0, stream>>>(PK, PV, Kp_hi, Kp_lo, Vpt);
    attn_kernel<<<1024, 256, ATTN_LDS_BYTES, stream>>>(Q, Kp_hi, Kp_lo, Vpt, out);
}

// Round 6
// 181.147 us; speedup vs baseline: 1.6598x; 1.1650x over previous
//
#include <hip/hip_runtime.h>

typedef __attribute__((ext_vector_type(8))) short bf16x8;
typedef __attribute__((ext_vector_type(8))) unsigned short u16x8;
typedef __attribute__((ext_vector_type(4))) float f32x4;

constexpr int BH  = 64;    // B*H
constexpr int SEQ = 4096;  // N
constexpr int DIM = 64;    // D
constexpr int PM  = 256;   // M (proj_len)
constexpr size_t PLANE = (size_t)BH * PM * DIM;   // 1,048,576 elements

__device__ __forceinline__ unsigned short f2bf(float f){
    unsigned int u = __float_as_uint(f);
    return (unsigned short)((u + 0x7fffu + ((u >> 16) & 1u)) >> 16);
}
__device__ __forceinline__ float bf2f(unsigned short h){
    return __uint_as_float(((unsigned int)h) << 16);
}
__device__ __forceinline__ unsigned short f2h(float f){
    _Float16 h = (_Float16)f;
    unsigned short u;
    __builtin_memcpy(&u, &h, 2);
    return u;
}
__device__ __forceinline__ float h2f(unsigned short u){
    _Float16 h;
    __builtin_memcpy(&h, &u, 2);
    return (float)h;
}

// ---------------- kernel 1: E [N][M] f32 -> Et_hi/Et_lo [M][N] bf16 (split) ----------------
__global__ __launch_bounds__(256) void prep_e_kernel(const float* __restrict__ E,
                                                     unsigned short* __restrict__ Et_hi,
                                                     unsigned short* __restrict__ Et_lo){
    __shared__ float T[64][65];
    int n0 = (blockIdx.x & 63) * 64;
    int m0 = (blockIdx.x >> 6) * 64;
    int t = threadIdx.x;
    #pragma unroll
    for (int i = 0; i < 16; ++i){
        int idx = t + i * 256;
        int nl = idx >> 6, ml = idx & 63;
        T[nl][ml] = E[(size_t)(n0 + nl) * PM + (m0 + ml)];
    }
    __syncthreads();
    #pragma unroll
    for (int i = 0; i < 16; ++i){
        int idx = t + i * 256;
        int ml = idx >> 6, nl = idx & 63;
        float v = T[nl][ml];
        unsigned short h = f2bf(v);
        unsigned short lo = f2bf(v - bf2f(h));
        size_t o = (size_t)(m0 + ml) * SEQ + (n0 + nl);
        Et_hi[o] = h;
        Et_lo[o] = lo;
    }
}

// ---------------- kernel 2: projection partials ----------------
// grid 1024 = 8 s-slices x (64 bh x 2 m-halves). s = bid&7 -> one n-slice per
// XCD (shared Et slice in L2); the two m-halves of a (bh,s) pair are adjacent
// in dispatch order -> same XCD, K/V tile L2-shared. Per wave: m-chunk of 32
// -> acc = 64 regs -> fits 4 waves/SIMD (4 blocks/CU).
// Outputs f16 partials PK[s][bh][m][d], PV[s][bh][d][m].
__global__ __launch_bounds__(256, 4) void proj_partial_kernel(const float* __restrict__ K,
                                                              const float* __restrict__ V,
                                                              const unsigned short* __restrict__ Et_hi,
                                                              const unsigned short* __restrict__ Et_lo,
                                                              unsigned short* __restrict__ PK,
                                                              unsigned short* __restrict__ PV){
    __shared__ unsigned short Kh[64][72], Kl[64][72], Vh[64][72];
    int bid   = blockIdx.x;
    int s     = bid & 7;
    int rest  = bid >> 3;          // 0..127
    int mh    = rest & 1;          // m-half: pair-adjacent in dispatch order
    int bh    = rest >> 1;
    int nbase = s * (SEQ / 8);
    int t = threadIdx.x;
    int w = t >> 6, l = t & 63, l15 = l & 15, lg = l >> 4;
    int m0w = mh * 128 + w * 32;   // wave's 32-row m-chunk

    const float* Kb = K + (size_t)bh * SEQ * DIM;
    const float* Vb = V + (size_t)bh * SEQ * DIM;
    int d  = t & 63;
    int ng = t >> 6;

    f32x4 accK[2][4], accV[4][2];  // [ms][dt] / [dt][ms]
    #pragma unroll
    for (int i = 0; i < 2; ++i)
        #pragma unroll
        for (int j = 0; j < 4; ++j){ accK[i][j] = (f32x4)0.0f; accV[j][i] = (f32x4)0.0f; }

    for (int n0 = nbase; n0 < nbase + SEQ / 8; n0 += 64){
        // stage K/V transposed + split: LDS [d][n] (short float live ranges)
        #pragma unroll
        for (int p = 0; p < 2; ++p){
            int nb = p * 32 + ng * 8;
            float kf[8], vf[8];
            #pragma unroll
            for (int i = 0; i < 8; ++i){
                kf[i] = Kb[(size_t)(n0 + nb + i) * DIM + d];
                vf[i] = Vb[(size_t)(n0 + nb + i) * DIM + d];
            }
            u16x8 kh, kl, vh;
            #pragma unroll
            for (int i = 0; i < 8; ++i){
                unsigned short h = f2bf(kf[i]);
                kh[i] = h;
                kl[i] = f2bf(kf[i] - bf2f(h));
                vh[i] = f2bf(vf[i]);
            }
            *reinterpret_cast<u16x8*>(&Kh[d][nb]) = kh;
            *reinterpret_cast<u16x8*>(&Kl[d][nb]) = kl;
            *reinterpret_cast<u16x8*>(&Vh[d][nb]) = vh;
        }
        __syncthreads();
        // Et fragments direct from global (L2-resident slice per XCD)
        bf16x8 eh[2][2], el[2][2];
        #pragma unroll
        for (int nk = 0; nk < 2; ++nk){
            #pragma unroll
            for (int ms = 0; ms < 2; ++ms){
                size_t off = (size_t)(m0w + ms * 16 + l15) * SEQ + (n0 + nk * 32 + lg * 8);
                eh[nk][ms] = *reinterpret_cast<const bf16x8*>(Et_hi + off);
                el[nk][ms] = *reinterpret_cast<const bf16x8*>(Et_lo + off);
            }
        }
        #pragma unroll
        for (int nk = 0; nk < 2; ++nk){
            int kb = nk * 32 + lg * 8;
            #pragma unroll
            for (int dt = 0; dt < 4; ++dt){
                bf16x8 kh = *reinterpret_cast<const bf16x8*>(&Kh[dt * 16 + l15][kb]);
                bf16x8 kl = *reinterpret_cast<const bf16x8*>(&Kl[dt * 16 + l15][kb]);
                bf16x8 vh = *reinterpret_cast<const bf16x8*>(&Vh[dt * 16 + l15][kb]);
                #pragma unroll
                for (int ms = 0; ms < 2; ++ms){
                    accK[ms][dt] = __builtin_amdgcn_mfma_f32_16x16x32_bf16(eh[nk][ms], kh, accK[ms][dt], 0, 0, 0);
                    accK[ms][dt] = __builtin_amdgcn_mfma_f32_16x16x32_bf16(eh[nk][ms], kl, accK[ms][dt], 0, 0, 0);
                    accK[ms][dt] = __builtin_amdgcn_mfma_f32_16x16x32_bf16(el[nk][ms], kh, accK[ms][dt], 0, 0, 0);
                    accV[dt][ms] = __builtin_amdgcn_mfma_f32_16x16x32_bf16(vh, eh[nk][ms], accV[dt][ms], 0, 0, 0);
                }
            }
        }
        __syncthreads();
    }

    // epilogue: f16 partial planes
    unsigned short* PKb = PK + ((size_t)s * BH + bh) * PM * DIM;
    unsigned short* PVb = PV + ((size_t)s * BH + bh) * DIM * PM;
    #pragma unroll
    for (int ms = 0; ms < 2; ++ms){
        #pragma unroll
        for (int dt = 0; dt < 4; ++dt){
            #pragma unroll
            for (int j = 0; j < 4; ++j){
                int mg = m0w + ms * 16 + lg * 4 + j;
                int dg = dt * 16 + l15;
                PKb[(size_t)mg * DIM + dg] = f2h(accK[ms][dt][j]);
                int dr = dt * 16 + lg * 4 + j;
                int mc = m0w + ms * 16 + l15;
                PVb[(size_t)dr * PM + mc] = f2h(accV[dt][ms][j]);
            }
        }
    }
}

// ---------------- kernel 2b: reduce 8 f16 partials -> Kp_hi/Kp_lo/Vpt ----------------
__global__ __launch_bounds__(256) void reduce_kernel(const unsigned short* __restrict__ PK,
                                                     const unsigned short* __restrict__ PV,
                                                     unsigned short* __restrict__ Kp_hi,
                                                     unsigned short* __restrict__ Kp_lo,
                                                     unsigned short* __restrict__ Vpt){
    size_t e8 = (size_t)blockIdx.x * 256 + threadIdx.x;   // one u16x8 per thread
    const u16x8* PK8 = reinterpret_cast<const u16x8*>(PK);
    const u16x8* PV8 = reinterpret_cast<const u16x8*>(PV);
    size_t stride8 = PLANE / 8;

    float k[8], v[8];
    {
        u16x8 a = PK8[e8];
        u16x8 b = PV8[e8];
        #pragma unroll
        for (int i = 0; i < 8; ++i){ k[i] = h2f(a[i]); v[i] = h2f(b[i]); }
    }
    #pragma unroll
    for (int s = 1; s < 8; ++s){
        u16x8 a = PK8[e8 + (size_t)s * stride8];
        u16x8 b = PV8[e8 + (size_t)s * stride8];
        #pragma unroll
        for (int i = 0; i < 8; ++i){ k[i] += h2f(a[i]); v[i] += h2f(b[i]); }
    }
    u16x8 hi, lo, vb;
    #pragma unroll
    for (int i = 0; i < 8; ++i){
        unsigned short h = f2bf(k[i]);
        hi[i] = h;
        lo[i] = f2bf(k[i] - bf2f(h));
        vb[i] = f2bf(v[i]);
    }
    *reinterpret_cast<u16x8*>(Kp_hi + e8 * 8) = hi;
    *reinterpret_cast<u16x8*>(Kp_lo + e8 * 8) = lo;
    *reinterpret_cast<u16x8*>(Vpt   + e8 * 8) = vb;
}

// ---------------- kernel 3: attention (unchanged from R5) ----------------
// grid 1024 = (bh x 16 q-chunks of 256). Stage the WHOLE head (Kp hi/lo + Vpt,
// 96 KB) in dynamic LDS once, ONE barrier, then 4 waves each process 64 q-rows
// (4 row-tiles of 16) with zero further barriers; P is wave-private LDS.
constexpr int ATTN_LDS_BYTES = (2 * 256 * 72 + 64 * 264 + 4 * 16 * 264) * 2;  // 141,312

__global__ __launch_bounds__(256, 1) void attn_kernel(const float* __restrict__ Q,
                                                      const unsigned short* __restrict__ Kp_hi,
                                                      const unsigned short* __restrict__ Kp_lo,
                                                      const unsigned short* __restrict__ Vpt,
                                                      float* __restrict__ Out){
    extern __shared__ unsigned short smem[];
    unsigned short (*Kh)[72]  = reinterpret_cast<unsigned short (*)[72]>(smem);              // [256][72]
    unsigned short (*Kl)[72]  = reinterpret_cast<unsigned short (*)[72]>(smem + 256 * 72);   // [256][72]
    unsigned short (*Vt)[264] = reinterpret_cast<unsigned short (*)[264]>(smem + 2 * 256 * 72); // [64][264]
    unsigned short* Pbase     = smem + 2 * 256 * 72 + 64 * 264;                              // 4 x [16][264]

    int bid  = blockIdx.x;
    int orig = (bid & 7) * 128 + (bid >> 3);  // XCD-chunked: 8 heads per XCD
    int bh   = orig >> 4;
    int q0   = (orig & 15) * 256;
    int t = threadIdx.x;
    int w = t >> 6, l = t & 63, l15 = l & 15, lg = l >> 4;
    unsigned short (*Pw)[264] = reinterpret_cast<unsigned short (*)[264]>(Pbase + w * 16 * 264);

    // ---- stage head slabs, flat & fully coalesced (16B per lane) ----
    const unsigned short* KHb = Kp_hi + (size_t)bh * PM * DIM;   // 16384 shorts
    const unsigned short* KLb = Kp_lo + (size_t)bh * PM * DIM;
    const unsigned short* VTb = Vpt   + (size_t)bh * DIM * PM;
    #pragma unroll
    for (int i = 0; i < 8; ++i){
        int idx = i * 256 + t;            // u16x8 index, 2048 vecs
        int r = idx >> 3;                 // 8 vecs per 64-short row
        int c = (idx & 7) * 8;
        u16x8 a = *reinterpret_cast<const u16x8*>(KHb + (size_t)idx * 8);
        u16x8 b = *reinterpret_cast<const u16x8*>(KLb + (size_t)idx * 8);
        *reinterpret_cast<u16x8*>(&Kh[r][c]) = a;
        *reinterpret_cast<u16x8*>(&Kl[r][c]) = b;
    }
    #pragma unroll
    for (int i = 0; i < 8; ++i){
        int idx = i * 256 + t;            // 2048 vecs
        int r = idx >> 5;                 // 32 vecs per 256-short row
        int c = (idx & 31) * 8;
        u16x8 a = *reinterpret_cast<const u16x8*>(VTb + (size_t)idx * 8);
        *reinterpret_cast<u16x8*>(&Vt[r][c]) = a;
    }
    __syncthreads();   // the ONLY barrier

    const float* Qw = Q   + ((size_t)bh * SEQ + q0 + w * 64) * DIM;
    float*       Ow = Out + ((size_t)bh * SEQ + q0 + w * 64) * DIM;

    for (int rt = 0; rt < 4; ++rt){
        // Q fragments (x 1/8 scale) straight from global, split hi/lo
        bf16x8 qh[2], ql[2];
        {
            const float* Qb = Qw + (size_t)(rt * 16 + l15) * DIM;
            #pragma unroll
            for (int nk = 0; nk < 2; ++nk){
                float4 a = *reinterpret_cast<const float4*>(Qb + nk * 32 + lg * 8);
                float4 b = *reinterpret_cast<const float4*>(Qb + nk * 32 + lg * 8 + 4);
                float vals[8] = {a.x, a.y, a.z, a.w, b.x, b.y, b.z, b.w};
                #pragma unroll
                for (int i = 0; i < 8; ++i){
                    float v = vals[i] * 0.125f;
                    unsigned short h = f2bf(v);
                    qh[nk][i] = (short)h;
                    ql[nk][i] = (short)f2bf(v - bf2f(h));
                }
            }
        }

        // QK^T from LDS
        f32x4 sa[16];
        #pragma unroll
        for (int i = 0; i < 16; ++i) sa[i] = (f32x4)0.0f;
        #pragma unroll
        for (int mi = 0; mi < 16; ++mi){
            #pragma unroll
            for (int nk = 0; nk < 2; ++nk){
                bf16x8 bh_ = *reinterpret_cast<const bf16x8*>(&Kh[mi * 16 + l15][nk * 32 + lg * 8]);
                bf16x8 bl_ = *reinterpret_cast<const bf16x8*>(&Kl[mi * 16 + l15][nk * 32 + lg * 8]);
                sa[mi] = __builtin_amdgcn_mfma_f32_16x16x32_bf16(qh[nk], bh_, sa[mi], 0, 0, 0);
                sa[mi] = __builtin_amdgcn_mfma_f32_16x16x32_bf16(qh[nk], bl_, sa[mi], 0, 0, 0);
                sa[mi] = __builtin_amdgcn_mfma_f32_16x16x32_bf16(ql[nk], bh_, sa[mi], 0, 0, 0);
            }
        }

        // softmax over m=256 (cols spread over 16 lanes x 16 regs; row = lg*4+j)
        float inv[4];
        #pragma unroll
        for (int j = 0; j < 4; ++j){
            float mx = sa[0][j];
            #pragma unroll
            for (int mi = 1; mi < 16; ++mi) mx = fmaxf(mx, sa[mi][j]);
            #pragma unroll
            for (int o = 1; o < 16; o <<= 1) mx = fmaxf(mx, __shfl_xor(mx, o, 64));
            float sum = 0.0f;
            #pragma unroll
            for (int mi = 0; mi < 16; ++mi){
                float p = __expf(sa[mi][j] - mx);
                sa[mi][j] = p;
                sum += p;
            }
            #pragma unroll
            for (int o = 1; o < 16; o <<= 1) sum += __shfl_xor(sum, o, 64);
            inv[j] = 1.0f / sum;
        }

        // wave-private P redistribution (no barrier; same-wave LDS RAW is ordered)
        #pragma unroll
        for (int mi = 0; mi < 16; ++mi){
            #pragma unroll
            for (int j = 0; j < 4; ++j){
                Pw[lg * 4 + j][mi * 16 + l15] = f2bf(sa[mi][j]);
            }
        }

        // PV from LDS
        f32x4 oacc[4];
        #pragma unroll
        for (int i = 0; i < 4; ++i) oacc[i] = (f32x4)0.0f;
        #pragma unroll
        for (int mk = 0; mk < 8; ++mk){
            bf16x8 ap = *reinterpret_cast<const bf16x8*>(&Pw[l15][mk * 32 + lg * 8]);
            #pragma unroll
            for (int dt = 0; dt < 4; ++dt){
                bf16x8 bv = *reinterpret_cast<const bf16x8*>(&Vt[dt * 16 + l15][mk * 32 + lg * 8]);
                oacc[dt] = __builtin_amdgcn_mfma_f32_16x16x32_bf16(ap, bv, oacc[dt], 0, 0, 0);
            }
        }

        #pragma unroll
        for (int dt = 0; dt < 4; ++dt){
            #pragma unroll
            for (int j = 0; j < 4; ++j){
                Ow[(size_t)(rt * 16 + lg * 4 + j) * DIM + dt * 16 + l15] = oacc[dt][j] * inv[j];
            }
        }
    }
}

extern "C" void kernel_launch(void* const* d_in, const int* in_sizes, int n_in,
                              void* d_out, int out_size, void* d_ws, size_t ws_size,
                              hipStream_t stream){
    const float* Q = (const float*)d_in[0];
    const float* K = (const float*)d_in[1];
    const float* V = (const float*)d_in[2];
    const float* E = (const float*)d_in[3];
    float* out = (float*)d_out;

    unsigned short* Et_hi = (unsigned short*)d_ws;                       // [M][N]
    unsigned short* Et_lo = Et_hi + (size_t)PM * SEQ;                    // [M][N]
    unsigned short* Kp_hi = Et_lo + (size_t)PM * SEQ;                    // [BH][M][D]
    unsigned short* Kp_lo = Kp_hi + PLANE;                               // [BH][M][D]
    unsigned short* Vpt   = Kp_lo + PLANE;                               // [BH][D][M]
    unsigned short* PK    = Vpt   + PLANE;                               // [8][BH][M][D] f16
    unsigned short* PV    = PK    + 8 * PLANE;                           // [8][BH][D][M] f16

    // opt-in to >64KB dynamic LDS (host-side attribute; graph-capture safe)
    hipFuncSetAttribute(reinterpret_cast<const void*>(attn_kernel),
                        hipFuncAttributeMaxDynamicSharedMemorySize, ATTN_LDS_BYTES);

    prep_e_kernel<<<256, 256, 0, stream>>>(E, Et_hi, Et_lo);
    proj_partial_kernel<<<1024, 256, 0, stream>>>(K, V, Et_hi, Et_lo, PK, PV);
    reduce_kernel<<<PLANE / 8 / 256, 256, 0, stream>>>(PK, PV, Kp_hi, Kp_lo, Vpt);
    attn_kernel<<<1024, 256, ATTN_LDS_BYTES, stream>>>(Q, Kp_hi, Kp_lo, Vpt, out);
}